// Round 1
// baseline (295.854 us; speedup 1.0000x reference)
//
#include <hip/hip_runtime.h>

#define TABLE_BITS 21
#define TABLE_SIZE (1u << TABLE_BITS)      // 2,097,152 entries > max key 1,999,999
#define TABLE_MASK (TABLE_SIZE - 1u)
#define BLOCK 256
#define EPT 4                              // elements per thread
#define CHUNK (BLOCK * EPT)                // 1024 elements per block
#define RANK_BIT 0x40000000
#define RANK_MASK 0x3FFFFFFF

// K1: first-occurrence index per key via atomicMin. Table pre-set to 0x7F7F7F7F.
__global__ __launch_bounds__(BLOCK) void k_first_idx(const int* __restrict__ x, int n,
                                                     int* __restrict__ table) {
    int base = (blockIdx.x * BLOCK + threadIdx.x) * EPT;
    if (base + EPT <= n) {
        int4 v = *reinterpret_cast<const int4*>(x + base);
        atomicMin(&table[(unsigned)v.x & TABLE_MASK], base);
        atomicMin(&table[(unsigned)v.y & TABLE_MASK], base + 1);
        atomicMin(&table[(unsigned)v.z & TABLE_MASK], base + 2);
        atomicMin(&table[(unsigned)v.w & TABLE_MASK], base + 3);
    } else {
        for (int i = base; i < n; ++i)
            atomicMin(&table[(unsigned)x[i] & TABLE_MASK], i);
    }
}

// K2: per-block count of first-occurrence flags (table[key] == position).
__global__ __launch_bounds__(BLOCK) void k_count(const int* __restrict__ x, int n,
                                                 const int* __restrict__ table,
                                                 int* __restrict__ blockSums) {
    int tid = threadIdx.x;
    int base = blockIdx.x * CHUNK + tid * EPT;
    int cnt = 0;
    if (base + EPT <= n) {
        int4 v = *reinterpret_cast<const int4*>(x + base);
        cnt += (table[(unsigned)v.x & TABLE_MASK] == base);
        cnt += (table[(unsigned)v.y & TABLE_MASK] == base + 1);
        cnt += (table[(unsigned)v.z & TABLE_MASK] == base + 2);
        cnt += (table[(unsigned)v.w & TABLE_MASK] == base + 3);
    } else {
        for (int i = base; i < n; ++i)
            cnt += (table[(unsigned)x[i] & TABLE_MASK] == i);
    }
    // wave64 reduce
    for (int off = 32; off > 0; off >>= 1)
        cnt += __shfl_down(cnt, off, 64);
    __shared__ int ws[BLOCK / 64];
    if ((tid & 63) == 0) ws[tid >> 6] = cnt;
    __syncthreads();
    if (tid == 0) {
        int s = 0;
        #pragma unroll
        for (int w = 0; w < BLOCK / 64; ++w) s += ws[w];
        blockSums[blockIdx.x] = s;
    }
}

// K3: single-block exclusive scan of blockSums (B entries, B ~ a few thousand).
__global__ __launch_bounds__(BLOCK) void k_scan(int* __restrict__ sums, int B) {
    __shared__ int lds[BLOCK];
    int tid = threadIdx.x;
    int carry = 0;
    for (int base = 0; base < B; base += BLOCK) {
        int idx = base + tid;
        int v = (idx < B) ? sums[idx] : 0;
        lds[tid] = v;
        __syncthreads();
        for (int off = 1; off < BLOCK; off <<= 1) {
            int t = (tid >= off) ? lds[tid - off] : 0;
            __syncthreads();
            lds[tid] += t;
            __syncthreads();
        }
        if (idx < B) sums[idx] = carry + lds[tid] - v;   // exclusive
        carry += lds[BLOCK - 1];
        __syncthreads();
    }
}

// K4: assign ranks to first occurrences; write rank|RANK_BIT into the table.
// Safe vs concurrent flag reads: (rank|RANK_BIT) can never equal a position index.
__global__ __launch_bounds__(BLOCK) void k_rank(const int* __restrict__ x, int n,
                                                int* __restrict__ table,
                                                const int* __restrict__ blockSums) {
    int tid = threadIdx.x;
    int base = blockIdx.x * CHUNK + tid * EPT;
    unsigned keys[EPT];
    int flags[EPT];
    int cnt = 0;
    if (base + EPT <= n) {
        int4 v = *reinterpret_cast<const int4*>(x + base);
        keys[0] = (unsigned)v.x & TABLE_MASK;
        keys[1] = (unsigned)v.y & TABLE_MASK;
        keys[2] = (unsigned)v.z & TABLE_MASK;
        keys[3] = (unsigned)v.w & TABLE_MASK;
        #pragma unroll
        for (int j = 0; j < EPT; ++j) {
            flags[j] = (table[keys[j]] == base + j);
            cnt += flags[j];
        }
    } else {
        #pragma unroll
        for (int j = 0; j < EPT; ++j) {
            flags[j] = 0;
            if (base + j < n) {
                keys[j] = (unsigned)x[base + j] & TABLE_MASK;
                flags[j] = (table[keys[j]] == base + j);
                cnt += flags[j];
            }
        }
    }
    // block exclusive scan of per-thread counts
    __shared__ int lds[BLOCK];
    lds[tid] = cnt;
    __syncthreads();
    for (int off = 1; off < BLOCK; off <<= 1) {
        int t = (tid >= off) ? lds[tid - off] : 0;
        __syncthreads();
        lds[tid] += t;
        __syncthreads();
    }
    int r = blockSums[blockIdx.x] + lds[tid] - cnt;
    #pragma unroll
    for (int j = 0; j < EPT; ++j)
        if (flags[j]) table[keys[j]] = (r++) | RANK_BIT;
}

// K5: gather rank, apply max_tokens cutoff, write output ids.
__global__ __launch_bounds__(BLOCK) void k_out(const int* __restrict__ x, int n,
                                               const int* __restrict__ table,
                                               const int* __restrict__ mtp,
                                               int* __restrict__ out) {
    int mt = mtp[0];
    int base = (blockIdx.x * BLOCK + threadIdx.x) * EPT;
    if (base + EPT <= n) {
        int4 v = *reinterpret_cast<const int4*>(x + base);
        int4 o;
        int r;
        r = table[(unsigned)v.x & TABLE_MASK] & RANK_MASK; o.x = (r < mt) ? r + 1 : 0;
        r = table[(unsigned)v.y & TABLE_MASK] & RANK_MASK; o.y = (r < mt) ? r + 1 : 0;
        r = table[(unsigned)v.z & TABLE_MASK] & RANK_MASK; o.z = (r < mt) ? r + 1 : 0;
        r = table[(unsigned)v.w & TABLE_MASK] & RANK_MASK; o.w = (r < mt) ? r + 1 : 0;
        *reinterpret_cast<int4*>(out + base) = o;
    } else {
        for (int i = base; i < n; ++i) {
            int r = table[(unsigned)x[i] & TABLE_MASK] & RANK_MASK;
            out[i] = (r < mt) ? r + 1 : 0;
        }
    }
}

extern "C" void kernel_launch(void* const* d_in, const int* in_sizes, int n_in,
                              void* d_out, int out_size, void* d_ws, size_t ws_size,
                              hipStream_t stream) {
    const int* x   = (const int*)d_in[0];
    const int* mtp = (const int*)d_in[1];
    int n = in_sizes[0];
    int* out = (int*)d_out;

    int* table     = (int*)d_ws;                                   // 8 MB
    int* blockSums = (int*)((char*)d_ws + TABLE_SIZE * sizeof(int));

    int B = (n + CHUNK - 1) / CHUNK;   // blocks for flag/rank kernels

    hipMemsetAsync(table, 0x7F, TABLE_SIZE * sizeof(int), stream); // "infinity"

    k_first_idx<<<(n + BLOCK * EPT - 1) / (BLOCK * EPT), BLOCK, 0, stream>>>(x, n, table);
    k_count    <<<B, BLOCK, 0, stream>>>(x, n, table, blockSums);
    k_scan     <<<1, BLOCK, 0, stream>>>(blockSums, B);
    k_rank     <<<B, BLOCK, 0, stream>>>(x, n, table, blockSums);
    k_out      <<<(n + BLOCK * EPT - 1) / (BLOCK * EPT), BLOCK, 0, stream>>>(x, n, table, mtp, out);
}

// Round 2
// 262.209 us; speedup vs baseline: 1.1283x; 1.1283x over previous
//
#include <hip/hip_runtime.h>
#include <limits.h>

#define TABLE_BITS 21
#define TABLE_SIZE (1u << TABLE_BITS)      // 2,097,152 entries > max key 1,999,999
#define TABLE_MASK (TABLE_SIZE - 1u)
#define BLOCK 256
#define EPT 4                              // elements per thread
#define CHUNK (BLOCK * EPT)                // 1024 elements per block
#define RANK_BIT 0x40000000
#define RANK_MASK 0x3FFFFFFF
#define NXCD 8

__device__ __forceinline__ unsigned xcc_id() {
    unsigned x;
    asm volatile("s_getreg_b32 %0, hwreg(HW_REG_XCC_ID)" : "=s"(x));
    return x & (NXCD - 1);
}

// ---------- K1a: per-XCD first-occurrence via L2-local atomics ----------
// Each block atomics into its own XCD's private 8MB table. WORKGROUP scope
// should emit global_atomic_smin without sc1 -> executes at the XCD's L2.
// Cross-XCD visibility comes from the implicit L2 writeback at kernel end.
__global__ __launch_bounds__(BLOCK) void k_first_idx_local(const int* __restrict__ x, int n,
                                                           int* __restrict__ tables) {
    int* tbl = tables + (size_t)xcc_id() * TABLE_SIZE;
    int base = (blockIdx.x * BLOCK + threadIdx.x) * EPT;
    if (base + EPT <= n) {
        int4 v = *reinterpret_cast<const int4*>(x + base);
        __hip_atomic_fetch_min(&tbl[(unsigned)v.x & TABLE_MASK], base,     __ATOMIC_RELAXED, __HIP_MEMORY_SCOPE_WORKGROUP);
        __hip_atomic_fetch_min(&tbl[(unsigned)v.y & TABLE_MASK], base + 1, __ATOMIC_RELAXED, __HIP_MEMORY_SCOPE_WORKGROUP);
        __hip_atomic_fetch_min(&tbl[(unsigned)v.z & TABLE_MASK], base + 2, __ATOMIC_RELAXED, __HIP_MEMORY_SCOPE_WORKGROUP);
        __hip_atomic_fetch_min(&tbl[(unsigned)v.w & TABLE_MASK], base + 3, __ATOMIC_RELAXED, __HIP_MEMORY_SCOPE_WORKGROUP);
    } else {
        for (int i = base; i < n; ++i)
            __hip_atomic_fetch_min(&tbl[(unsigned)x[i] & TABLE_MASK], i, __ATOMIC_RELAXED, __HIP_MEMORY_SCOPE_WORKGROUP);
    }
}

// K1b: merge the 8 per-XCD tables into the canonical table (element-wise min).
__global__ __launch_bounds__(BLOCK) void k_merge(const int* __restrict__ tables,
                                                 int* __restrict__ table) {
    int idx = (blockIdx.x * BLOCK + threadIdx.x) * 4;
    int4 m = *reinterpret_cast<const int4*>(tables + idx);
    #pragma unroll
    for (int k = 1; k < NXCD; ++k) {
        int4 t = *reinterpret_cast<const int4*>(tables + (size_t)k * TABLE_SIZE + idx);
        m.x = min(m.x, t.x); m.y = min(m.y, t.y);
        m.z = min(m.z, t.z); m.w = min(m.w, t.w);
    }
    *reinterpret_cast<int4*>(table + idx) = m;
}

// ---------- K1 fallback: device-scope atomicMin into single table ----------
__global__ __launch_bounds__(BLOCK) void k_first_idx(const int* __restrict__ x, int n,
                                                     int* __restrict__ table) {
    int base = (blockIdx.x * BLOCK + threadIdx.x) * EPT;
    if (base + EPT <= n) {
        int4 v = *reinterpret_cast<const int4*>(x + base);
        atomicMin(&table[(unsigned)v.x & TABLE_MASK], base);
        atomicMin(&table[(unsigned)v.y & TABLE_MASK], base + 1);
        atomicMin(&table[(unsigned)v.z & TABLE_MASK], base + 2);
        atomicMin(&table[(unsigned)v.w & TABLE_MASK], base + 3);
    } else {
        for (int i = base; i < n; ++i)
            atomicMin(&table[(unsigned)x[i] & TABLE_MASK], i);
    }
}

// ---------- K2: count first-occurrence flags + publish packed bitmask ----------
__global__ __launch_bounds__(BLOCK) void k_count(const int* __restrict__ x, int n,
                                                 const int* __restrict__ table,
                                                 int* __restrict__ blockSums,
                                                 unsigned long long* __restrict__ bitmask) {
    int tid = threadIdx.x;
    int lane = tid & 63, w = tid >> 6;
    int base = blockIdx.x * CHUNK + tid * EPT;
    int flags[EPT];
    if (base + EPT <= n) {
        int4 v = *reinterpret_cast<const int4*>(x + base);
        flags[0] = (table[(unsigned)v.x & TABLE_MASK] == base);
        flags[1] = (table[(unsigned)v.y & TABLE_MASK] == base + 1);
        flags[2] = (table[(unsigned)v.z & TABLE_MASK] == base + 2);
        flags[3] = (table[(unsigned)v.w & TABLE_MASK] == base + 3);
    } else {
        #pragma unroll
        for (int j = 0; j < EPT; ++j) {
            flags[j] = 0;
            if (base + j < n)
                flags[j] = (table[(unsigned)x[base + j] & TABLE_MASK] == base + j);
        }
    }
    int cnt = 0;
    #pragma unroll
    for (int j = 0; j < EPT; ++j) {
        unsigned long long mj = __ballot(flags[j]);
        if (lane == 0) bitmask[((size_t)blockIdx.x * (BLOCK / 64) + w) * EPT + j] = mj;
        cnt += flags[j];
    }
    // wave64 reduce
    for (int off = 32; off > 0; off >>= 1)
        cnt += __shfl_down(cnt, off, 64);
    __shared__ int ws[BLOCK / 64];
    if (lane == 0) ws[w] = cnt;
    __syncthreads();
    if (tid == 0) {
        int s = 0;
        #pragma unroll
        for (int q = 0; q < BLOCK / 64; ++q) s += ws[q];
        blockSums[blockIdx.x] = s;
    }
}

// ---------- K3: single-block exclusive scan of blockSums ----------
__global__ __launch_bounds__(BLOCK) void k_scan(int* __restrict__ sums, int B) {
    __shared__ int lds[BLOCK];
    int tid = threadIdx.x;
    int carry = 0;
    for (int base = 0; base < B; base += BLOCK) {
        int idx = base + tid;
        int v = (idx < B) ? sums[idx] : 0;
        lds[tid] = v;
        __syncthreads();
        for (int off = 1; off < BLOCK; off <<= 1) {
            int t = (tid >= off) ? lds[tid - off] : 0;
            __syncthreads();
            lds[tid] += t;
            __syncthreads();
        }
        if (idx < B) sums[idx] = carry + lds[tid] - v;   // exclusive
        carry += lds[BLOCK - 1];
        __syncthreads();
    }
}

// ---------- K4: assign ranks using the bitmask (no table gathers) ----------
__global__ __launch_bounds__(BLOCK) void k_rank(const int* __restrict__ x, int n,
                                                int* __restrict__ table,
                                                const int* __restrict__ blockSums,
                                                const unsigned long long* __restrict__ bitmask) {
    int tid = threadIdx.x;
    int lane = tid & 63, w = tid >> 6;
    int base = blockIdx.x * CHUNK + tid * EPT;
    const unsigned long long* bm = bitmask + ((size_t)blockIdx.x * (BLOCK / 64) + w) * EPT;
    int flags[EPT];
    int cnt = 0;
    #pragma unroll
    for (int j = 0; j < EPT; ++j) {
        flags[j] = (int)((bm[j] >> lane) & 1ull);
        cnt += flags[j];
    }
    // block exclusive scan of per-thread counts
    __shared__ int lds[BLOCK];
    lds[tid] = cnt;
    __syncthreads();
    for (int off = 1; off < BLOCK; off <<= 1) {
        int t = (tid >= off) ? lds[tid - off] : 0;
        __syncthreads();
        lds[tid] += t;
        __syncthreads();
    }
    int r = blockSums[blockIdx.x] + lds[tid] - cnt;
    if (cnt) {
        if (base + EPT <= n) {
            int4 v = *reinterpret_cast<const int4*>(x + base);
            if (flags[0]) table[(unsigned)v.x & TABLE_MASK] = (r++) | RANK_BIT;
            if (flags[1]) table[(unsigned)v.y & TABLE_MASK] = (r++) | RANK_BIT;
            if (flags[2]) table[(unsigned)v.z & TABLE_MASK] = (r++) | RANK_BIT;
            if (flags[3]) table[(unsigned)v.w & TABLE_MASK] = (r++) | RANK_BIT;
        } else {
            #pragma unroll
            for (int j = 0; j < EPT; ++j)
                if (flags[j]) table[(unsigned)x[base + j] & TABLE_MASK] = (r++) | RANK_BIT;
        }
    }
}

// ---------- K5: gather rank, apply max_tokens cutoff, write output ----------
__global__ __launch_bounds__(BLOCK) void k_out(const int* __restrict__ x, int n,
                                               const int* __restrict__ table,
                                               const int* __restrict__ mtp,
                                               int* __restrict__ out) {
    int mt = mtp[0];
    int base = (blockIdx.x * BLOCK + threadIdx.x) * EPT;
    if (base + EPT <= n) {
        int4 v = *reinterpret_cast<const int4*>(x + base);
        int4 o;
        int r;
        r = table[(unsigned)v.x & TABLE_MASK] & RANK_MASK; o.x = (r < mt) ? r + 1 : 0;
        r = table[(unsigned)v.y & TABLE_MASK] & RANK_MASK; o.y = (r < mt) ? r + 1 : 0;
        r = table[(unsigned)v.z & TABLE_MASK] & RANK_MASK; o.z = (r < mt) ? r + 1 : 0;
        r = table[(unsigned)v.w & TABLE_MASK] & RANK_MASK; o.w = (r < mt) ? r + 1 : 0;
        *reinterpret_cast<int4*>(out + base) = o;
    } else {
        for (int i = base; i < n; ++i) {
            int r = table[(unsigned)x[i] & TABLE_MASK] & RANK_MASK;
            out[i] = (r < mt) ? r + 1 : 0;
        }
    }
}

extern "C" void kernel_launch(void* const* d_in, const int* in_sizes, int n_in,
                              void* d_out, int out_size, void* d_ws, size_t ws_size,
                              hipStream_t stream) {
    const int* x   = (const int*)d_in[0];
    const int* mtp = (const int*)d_in[1];
    int n = in_sizes[0];
    int* out = (int*)d_out;

    const size_t tbytes = (size_t)TABLE_SIZE * sizeof(int);
    const size_t need_local = tbytes * (1 + NXCD) + (2u << 20);
    bool use_local = (ws_size >= need_local);

    int* table  = (int*)d_ws;                          // 8 MB canonical table
    int* tables = table + TABLE_SIZE;                  // 8 x 8 MB per-XCD (local path)
    char* extra = (char*)d_ws + (use_local ? tbytes * (1 + NXCD) : tbytes);
    int* blockSums = (int*)extra;                      // 64 KB region
    unsigned long long* bitmask = (unsigned long long*)(extra + 65536);

    int B = (n + CHUNK - 1) / CHUNK;

    if (use_local) {
        hipMemsetAsync(tables, 0x7F, tbytes * NXCD, stream);   // "infinity" in all 8
        k_first_idx_local<<<(n + CHUNK - 1) / CHUNK, BLOCK, 0, stream>>>(x, n, tables);
        k_merge<<<TABLE_SIZE / (BLOCK * 4), BLOCK, 0, stream>>>(tables, table);
    } else {
        hipMemsetAsync(table, 0x7F, tbytes, stream);
        k_first_idx<<<(n + CHUNK - 1) / CHUNK, BLOCK, 0, stream>>>(x, n, table);
    }
    k_count<<<B, BLOCK, 0, stream>>>(x, n, table, blockSums, bitmask);
    k_scan <<<1, BLOCK, 0, stream>>>(blockSums, B);
    k_rank <<<B, BLOCK, 0, stream>>>(x, n, table, blockSums, bitmask);
    k_out  <<<(n + CHUNK - 1) / CHUNK, BLOCK, 0, stream>>>(x, n, table, mtp, out);
}